// Round 1
// baseline (21.567 us; speedup 1.0000x reference)
//
#include <hip/hip_runtime.h>

#define N_LAYERS 512
#define DEL_Z (0.9f / 512.0f)

// Per-layer constants hoisted out of the per-element scan:
//   inv1 = 1/(PiT*(1-z)); inv2 = inv1/(1-z); g = 1 - b2/b1
//   c0 = 1+g
//   c1 = g*inv1 - DEL_Z*inv2
//   c3 = inv1^2 - inv2/PiT + 1/b1^2
//   c4 = DEL_Z * z^2 / b1        (MU^2 == 1)
// Per-step (exact algebra of the reference):
//   Rn = c0*Re + c1 + 2*DEL_Z*om*Im*(Re + inv1)
//   Im = c0*Im + DEL_Z*om*(Im^2 - (Rn+inv1)^2 + c3) - c4/om
__global__ __launch_bounds__(256) void metric_scan_kernel(
    const float* __restrict__ Re_s, const float* __restrict__ Im_s,
    const float* __restrict__ omega, const float* __restrict__ PiT_p,
    const float* __restrict__ B, float* __restrict__ out, int n)
{
    __shared__ float4 cA[N_LAYERS];   // {c0, c1, inv1, c3}
    __shared__ float  cB[N_LAYERS];   // c4

    const float PiT = PiT_p[0];
    for (int l = threadIdx.x; l < N_LAYERS; l += 256) {
        const float z    = DEL_Z * (float)l;   // Z_INI == 0
        const float b1   = B[l];
        const float b2   = B[l + 1];
        const float omz  = 1.0f - z;
        const float inv1 = 1.0f / (PiT * omz);
        const float inv2 = inv1 / omz;
        const float g    = 1.0f - b2 / b1;
        const float c0   = 1.0f + g;
        const float c1   = g * inv1 - DEL_Z * inv2;
        const float c3   = inv1 * inv1 - inv2 / PiT + 1.0f / (b1 * b1);
        const float c4   = DEL_Z * z * z / b1;
        cA[l] = make_float4(c0, c1, inv1, c3);
        cB[l] = c4;
    }
    __syncthreads();

    const int i = blockIdx.x * 256 + threadIdx.x;
    float Re = Re_s[i];
    float Im = Im_s[i];
    const float om    = omega[i];
    const float dzom  = DEL_Z * om;
    const float dz2om = 2.0f * dzom;
    const float iom   = 1.0f / om;

    #pragma unroll 8
    for (int l = 0; l < N_LAYERS; ++l) {
        const float4 c  = cA[l];
        const float  c4 = cB[l];
        const float  t  = Re + c.z;                  // Re + inv1
        const float  a  = fmaf(c.x, Re, c.y);        // c0*Re + c1
        const float  Rn = fmaf(dz2om * Im, t, a);
        const float  u  = Rn + c.z;                  // Rn + inv1
        float s = fmaf(Im, Im, c.w);                 // Im^2 + c3
        s = fmaf(-u, u, s);                          // Im^2 - u^2 + c3
        const float b = fmaf(c.x, Im, -(c4 * iom));  // c0*Im - c4/om
        Im = fmaf(dzom, s, b);
        Re = Rn;
    }

    out[i]     = Re;
    out[n + i] = Im;
}

extern "C" void kernel_launch(void* const* d_in, const int* in_sizes, int n_in,
                              void* d_out, int out_size, void* d_ws, size_t ws_size,
                              hipStream_t stream)
{
    const float* Re_s  = (const float*)d_in[0];
    const float* Im_s  = (const float*)d_in[1];
    const float* omega = (const float*)d_in[2];
    const float* PiT   = (const float*)d_in[3];
    const float* B     = (const float*)d_in[4];
    float* out = (float*)d_out;
    const int n = in_sizes[0];          // 131072
    metric_scan_kernel<<<n / 256, 256, 0, stream>>>(Re_s, Im_s, omega, PiT, B, out, n);
}